// Round 2
// baseline (140.211 us; speedup 1.0000x reference)
//
#include <hip/hip_runtime.h>
#include <math.h>

#define NB    16
#define CT    320
#define NPTS  1024
#define DFEAT 256
#define DPOS  64
#define KSEL  32
#define ROWS  32

// One block: 256 threads (4 waves), handles 32 consecutive rows of one batch.
// Phases: [pos stage+norm] -> [sim outer-product, acc in regs] ->
//         [4x (sim->LDS, quantized-threshold top-32, softmax)] -> [feat gather].
__global__ __launch_bounds__(256, 2) void gnn_fused(const float* __restrict__ in,
                                                    float* __restrict__ out) {
  __shared__ float pi[DPOS * 36];      // [d][i], stride 36 (16B-aligned float4 rows)
  __shared__ float rni[ROWS];
  __shared__ float simb[8 * 1028];     // 8 sim rows; later aliased as feat stage
  __shared__ float topv[ROWS][36];     // top values, then attn (overwritten)
  __shared__ int   topid[ROWS][36];

  const int p     = blockIdx.x;
  // XCD swizzle: 8 XCDs, round-robin dispatch assumed -> 2 batches per XCD.
  const int batch = ((p & 7) << 1) + ((p >> 3) & 1);
  const int chunk = p >> 4;            // 0..31
  const int i0    = chunk * ROWS;
  const int tid   = threadIdx.x;
  const int w     = tid >> 6;          // wave 0..3
  const int lane  = tid & 63;

  const float* __restrict__ fbase = in + (size_t)batch * CT * NPTS;   // feat channels [256][1024]
  const float* __restrict__ pbase = fbase + (size_t)DFEAT * NPTS;     // pos channels  [64][1024]

  // ---- stage raw pos of this block's 32 rows: pi[d][i] ----
  {
    const int i = tid & 31;
    const int d0 = tid >> 5;           // 0..7
#pragma unroll
    for (int pass = 0; pass < 8; ++pass) {
      const int d = pass * 8 + d0;
      pi[d * 36 + i] = pbase[(size_t)d * NPTS + i0 + i];
    }
  }
  __syncthreads();
  if (tid < ROWS) {
    float s = 0.f;
#pragma unroll
    for (int d = 0; d < DPOS; ++d) { const float x = pi[d * 36 + tid]; s = fmaf(x, x, s); }
    rni[tid] = 1.0f / fmaxf(sqrtf(s), 1e-12f);
  }
  __syncthreads();

  // ---- sim: wave w owns j in [w*256, w*256+256); lane owns 4 consecutive j ----
  float acc[ROWS][4];
#pragma unroll
  for (int r = 0; r < ROWS; ++r) { acc[r][0] = 0.f; acc[r][1] = 0.f; acc[r][2] = 0.f; acc[r][3] = 0.f; }
  float ssq0 = 0.f, ssq1 = 0.f, ssq2 = 0.f, ssq3 = 0.f;
  const float* jp = pbase + w * 256 + lane * 4;
#pragma unroll 2
  for (int d = 0; d < DPOS; ++d) {
    const float4 jv = *(const float4*)(jp + (size_t)d * NPTS);
    ssq0 = fmaf(jv.x, jv.x, ssq0);
    ssq1 = fmaf(jv.y, jv.y, ssq1);
    ssq2 = fmaf(jv.z, jv.z, ssq2);
    ssq3 = fmaf(jv.w, jv.w, ssq3);
#pragma unroll
    for (int rr = 0; rr < 8; ++rr) {
      const float4 p4 = *(const float4*)&pi[d * 36 + rr * 4];   // broadcast, conflict-free
      const float pv[4] = {p4.x, p4.y, p4.z, p4.w};
#pragma unroll
      for (int u = 0; u < 4; ++u) {
        acc[rr * 4 + u][0] = fmaf(pv[u], jv.x, acc[rr * 4 + u][0]);
        acc[rr * 4 + u][1] = fmaf(pv[u], jv.y, acc[rr * 4 + u][1]);
        acc[rr * 4 + u][2] = fmaf(pv[u], jv.z, acc[rr * 4 + u][2]);
        acc[rr * 4 + u][3] = fmaf(pv[u], jv.w, acc[rr * 4 + u][3]);
      }
    }
  }
  const float rnj0 = 1.0f / fmaxf(sqrtf(ssq0), 1e-12f);
  const float rnj1 = 1.0f / fmaxf(sqrtf(ssq1), 1e-12f);
  const float rnj2 = 1.0f / fmaxf(sqrtf(ssq2), 1e-12f);
  const float rnj3 = 1.0f / fmaxf(sqrtf(ssq3), 1e-12f);

  // ---- per 8-row group: sims -> LDS, exact top-32 set, softmax ----
#pragma unroll
  for (int g = 0; g < 4; ++g) {
#pragma unroll
    for (int rr = 0; rr < 8; ++rr) {
      const int r = g * 8 + rr;
      const float sc = rni[r];
      float4 sv;
      sv.x = acc[r][0] * rnj0 * sc;
      sv.y = acc[r][1] * rnj1 * sc;
      sv.z = acc[r][2] * rnj2 * sc;
      sv.w = acc[r][3] * rnj3 * sc;
      *(float4*)&simb[rr * 1028 + w * 256 + lane * 4] = sv;
    }
    __syncthreads();

    for (int rw = 0; rw < 2; ++rw) {
      const int rloc  = w * 2 + rw;       // 0..7
      const int rglob = g * 8 + rloc;
      // lane owns j = lane*16 .. lane*16+15 (strictly increasing in t)
      float v[16];
#pragma unroll
      for (int u = 0; u < 4; ++u) {
        const float4 t4 = *(const float4*)&simb[rloc * 1028 + lane * 16 + u * 4];
        v[u * 4 + 0] = t4.x; v[u * 4 + 1] = t4.y; v[u * 4 + 2] = t4.z; v[u * 4 + 3] = t4.w;
      }
      // monotone 10-bit quantization of v in [-1,1]
      int q[16];
#pragma unroll
      for (int t = 0; t < 16; ++t) {
        float f = (v[t] + 1.0f) * 512.0f;
        f = fminf(fmaxf(f, 0.0f), 1023.0f);
        q[t] = (int)f;
      }
      // binary search: largest lo with count(q >= lo) >= 32
      int lo = 0;
#pragma unroll
      for (int bit = 512; bit >= 1; bit >>= 1) {
        const int mid = lo + bit;
        int cnt = 0;
#pragma unroll
        for (int t = 0; t < 16; ++t) cnt += (int)__popcll(__ballot(q[t] >= mid));
        if (cnt >= KSEL) lo = mid;
      }
      // compact definite members (q > lo): strictly greater values than boundary bin
      int cbase = 0;
      unsigned cmask = 0u;
      const int thr = lo + 1;
#pragma unroll
      for (int t = 0; t < 16; ++t) {
        const bool hi = (q[t] >= thr);
        const unsigned long long m = __ballot(hi);
        if (hi) {
          const int pos = cbase + (int)__builtin_amdgcn_mbcnt_hi(
              (unsigned)(m >> 32), __builtin_amdgcn_mbcnt_lo((unsigned)m, 0u));
          topv[rglob][pos]  = v[t];
          topid[rglob][pos] = lane * 16 + t;
        }
        cbase += (int)__popcll(m);
        if (q[t] == lo) cmask |= (1u << t);
      }
      // boundary bin: exact (v desc, j asc) selection for remaining slots
      const int need = KSEL - cbase;
      for (int it = 0; it < need; ++it) {
        float bv = -2.0f; int bj = 0x7fffffff; int bt = 16;
#pragma unroll
        for (int t = 0; t < 16; ++t) {
          if (((cmask >> t) & 1u) && v[t] > bv) { bv = v[t]; bj = lane * 16 + t; bt = t; }
        }
        float rv = bv; int rj = bj;
#pragma unroll
        for (int s = 1; s < 64; s <<= 1) {
          const float ov = __shfl_xor(rv, s);
          const int   oj = __shfl_xor(rj, s);
          if (ov > rv || (ov == rv && oj < rj)) { rv = ov; rj = oj; }
        }
        if (bv == rv && bj == rj) {        // unique winner (j unique)
          topv[rglob][cbase + it]  = bv;
          topid[rglob][cbase + it] = bj;
          cmask &= ~(1u << bt);
        }
      }
      // softmax over the 32 values (order-invariant)
      {
        const float x = topv[rglob][lane & 31];
        float mx = x;
#pragma unroll
        for (int s = 16; s >= 1; s >>= 1) mx = fmaxf(mx, __shfl_xor(mx, s));
        const float e = expf(x - mx);
        float sum = e;
#pragma unroll
        for (int s = 16; s >= 1; s >>= 1) sum += __shfl_xor(sum, s);
        if (lane < KSEL) topv[rglob][lane] = e / sum;   // overwrite values with attn
      }
    }
    __syncthreads();
  }

  // ---- gather: per-lane attn/ids in regs; feat staged 8 channels at a time ----
  const int row = lane & 31;
  float ar[KSEL]; int ir[KSEL];
#pragma unroll
  for (int k4 = 0; k4 < 8; ++k4) {
    const float4 av = *(const float4*)&topv[row][k4 * 4];
    ar[k4 * 4 + 0] = av.x; ar[k4 * 4 + 1] = av.y; ar[k4 * 4 + 2] = av.z; ar[k4 * 4 + 3] = av.w;
    const int4 iv = *(const int4*)&topid[row][k4 * 4];
    ir[k4 * 4 + 0] = iv.x; ir[k4 * 4 + 1] = iv.y; ir[k4 * 4 + 2] = iv.z; ir[k4 * 4 + 3] = iv.w;
  }
  const int cslot = (w << 1) + (lane >> 5);   // 0..7
  float* const fst = simb;                     // alias sim buffer as feat stage
  for (int cc = 0; cc < 32; ++cc) {
    __syncthreads();                           // prev compute done before overwrite
    {
      const int cr = tid >> 5;                 // 0..7
      const int jb = (tid & 31) * 4;
      const float* src = fbase + (size_t)(cc * 8 + cr) * NPTS;
#pragma unroll
      for (int u = 0; u < 8; ++u)
        *(float4*)&fst[cr * 1028 + u * 128 + jb] = *(const float4*)&src[u * 128 + jb];
    }
    __syncthreads();
    float o = 0.f;
    const float* frow = &fst[cslot * 1028];
#pragma unroll
    for (int k = 0; k < KSEL; ++k) o = fmaf(ar[k], frow[ir[k]], o);
    out[((size_t)batch * DFEAT + cc * 8 + cslot) * NPTS + i0 + row] = o;
  }
}

extern "C" void kernel_launch(void* const* d_in, const int* in_sizes, int n_in,
                              void* d_out, int out_size, void* d_ws, size_t ws_size,
                              hipStream_t stream) {
  const float* in = (const float*)d_in[0];
  float* out = (float*)d_out;
  gnn_fused<<<dim3(512), dim3(256), 0, stream>>>(in, out);
}

// Round 3
// 123.688 us; speedup vs baseline: 1.1336x; 1.1336x over previous
//
#include <hip/hip_runtime.h>
#include <math.h>

#define CT    320
#define NPTS  1024
#define DFEAT 256
#define DPOS  64
#define KSEL  32

// ================= Kernel A: sim + exact top-32 + softmax -> pairs(ws) ======
// 1024 blocks x 256 threads; 16 rows/block; 3 blocks/CU (LDS 42.7KB).
#define AROWS 16
__global__ __launch_bounds__(256, 3) void gnn_sim_topk(const float* __restrict__ in,
                                                       float2* __restrict__ pairs) {
  __shared__ float pi[DPOS * 20];      // [d][i], stride 20 (16B-aligned quads)
  __shared__ float rni[AROWS];
  __shared__ float simb[8 * 1028];     // 8 sim rows, quad-XOR-swizzled
  __shared__ float topv[AROWS][36];
  __shared__ int   topid[AROWS][36];

  const int p     = blockIdx.x;
  const int batch = ((p & 7) << 1) | ((p >> 3) & 1);   // 2 batches per XCD
  const int chunk = p >> 4;            // 0..63
  const int i0    = chunk * AROWS;
  const int tid   = threadIdx.x;
  const int w     = tid >> 6;
  const int lane  = tid & 63;

  const float* __restrict__ fbase = in + (size_t)batch * CT * NPTS;
  const float* __restrict__ pbase = fbase + (size_t)DFEAT * NPTS;

  // stage raw pos of the 16 rows
  {
    const int i = tid & 15;
    const int d0 = tid >> 4;           // 0..15
#pragma unroll
    for (int pass = 0; pass < 4; ++pass) {
      const int d = pass * 16 + d0;
      pi[d * 20 + i] = pbase[(size_t)d * NPTS + i0 + i];
    }
  }
  __syncthreads();
  if (tid < AROWS) {
    float s = 0.f;
#pragma unroll
    for (int d = 0; d < DPOS; ++d) { const float x = pi[d * 20 + tid]; s = fmaf(x, x, s); }
    rni[tid] = 1.0f / fmaxf(sqrtf(s), 1e-12f);
  }
  __syncthreads();

  // sim outer-product: wave w owns j in [w*256, (w+1)*256), lane owns 4 j
  float acc[AROWS][4];
#pragma unroll
  for (int r = 0; r < AROWS; ++r) { acc[r][0]=0.f; acc[r][1]=0.f; acc[r][2]=0.f; acc[r][3]=0.f; }
  float ssq0=0.f, ssq1=0.f, ssq2=0.f, ssq3=0.f;
  const float* jp = pbase + w * 256 + lane * 4;
#pragma unroll 2
  for (int d = 0; d < DPOS; ++d) {
    const float4 jv = *(const float4*)(jp + (size_t)d * NPTS);
    ssq0 = fmaf(jv.x, jv.x, ssq0);
    ssq1 = fmaf(jv.y, jv.y, ssq1);
    ssq2 = fmaf(jv.z, jv.z, ssq2);
    ssq3 = fmaf(jv.w, jv.w, ssq3);
#pragma unroll
    for (int rr = 0; rr < 4; ++rr) {
      const float4 p4 = *(const float4*)&pi[d * 20 + rr * 4];   // broadcast
      const float pv[4] = {p4.x, p4.y, p4.z, p4.w};
#pragma unroll
      for (int u = 0; u < 4; ++u) {
        acc[rr*4+u][0] = fmaf(pv[u], jv.x, acc[rr*4+u][0]);
        acc[rr*4+u][1] = fmaf(pv[u], jv.y, acc[rr*4+u][1]);
        acc[rr*4+u][2] = fmaf(pv[u], jv.z, acc[rr*4+u][2]);
        acc[rr*4+u][3] = fmaf(pv[u], jv.w, acc[rr*4+u][3]);
      }
    }
  }
  const float rnj0 = 1.0f / fmaxf(sqrtf(ssq0), 1e-12f);
  const float rnj1 = 1.0f / fmaxf(sqrtf(ssq1), 1e-12f);
  const float rnj2 = 1.0f / fmaxf(sqrtf(ssq2), 1e-12f);
  const float rnj3 = 1.0f / fmaxf(sqrtf(ssq3), 1e-12f);

#pragma unroll
  for (int g = 0; g < 2; ++g) {
#pragma unroll
    for (int rr = 0; rr < 8; ++rr) {
      const int r = g * 8 + rr;
      const float sc = rni[r];
      float4 sv;
      sv.x = acc[r][0] * rnj0 * sc;
      sv.y = acc[r][1] * rnj1 * sc;
      sv.z = acc[r][2] * rnj2 * sc;
      sv.w = acc[r][3] * rnj3 * sc;
      // quad-XOR swizzle: logical quad lq -> phys lq ^ ((lq>>3)&7)
      const int lq = w * 64 + lane;
      const int pq = lq ^ ((lq >> 3) & 7);
      *(float4*)&simb[rr * 1028 + pq * 4] = sv;
    }
    __syncthreads();

    for (int rw = 0; rw < 2; ++rw) {
      const int rloc  = w * 2 + rw;
      const int rglob = g * 8 + rloc;
      float v[16];
#pragma unroll
      for (int u = 0; u < 4; ++u) {
        const int lq = lane * 4 + u;
        const int pq = lq ^ ((lq >> 3) & 7);
        const float4 t4 = *(const float4*)&simb[rloc * 1028 + pq * 4];
        v[u*4+0]=t4.x; v[u*4+1]=t4.y; v[u*4+2]=t4.z; v[u*4+3]=t4.w;
      }
      int q[16];
#pragma unroll
      for (int t = 0; t < 16; ++t) {
        float f = (v[t] + 1.0f) * 512.0f;
        f = fminf(fmaxf(f, 0.0f), 1023.0f);
        q[t] = (int)f;
      }
      int lo = 0;
#pragma unroll
      for (int bit = 512; bit >= 1; bit >>= 1) {
        const int mid = lo + bit;
        int cnt = 0;
#pragma unroll
        for (int t = 0; t < 16; ++t) cnt += (int)__popcll(__ballot(q[t] >= mid));
        if (cnt >= KSEL) lo = mid;
      }
      int cbase = 0;
      unsigned cmask = 0u;
      const int thr = lo + 1;
#pragma unroll
      for (int t = 0; t < 16; ++t) {
        const bool hi = (q[t] >= thr);
        const unsigned long long m = __ballot(hi);
        if (hi) {
          const int pos = cbase + (int)__builtin_amdgcn_mbcnt_hi(
              (unsigned)(m >> 32), __builtin_amdgcn_mbcnt_lo((unsigned)m, 0u));
          topv[rglob][pos]  = v[t];
          topid[rglob][pos] = lane * 16 + t;
        }
        cbase += (int)__popcll(m);
        if (q[t] == lo) cmask |= (1u << t);
      }
      const int need = KSEL - cbase;
      for (int it = 0; it < need; ++it) {
        float bv = -2.0f; int bj = 0x7fffffff; int bt = 16;
#pragma unroll
        for (int t = 0; t < 16; ++t) {
          if (((cmask >> t) & 1u) && v[t] > bv) { bv = v[t]; bj = lane * 16 + t; bt = t; }
        }
        float rv = bv; int rj = bj;
#pragma unroll
        for (int s = 1; s < 64; s <<= 1) {
          const float ov = __shfl_xor(rv, s);
          const int   oj = __shfl_xor(rj, s);
          if (ov > rv || (ov == rv && oj < rj)) { rv = ov; rj = oj; }
        }
        if (bv == rv && bj == rj) {
          topv[rglob][cbase + it]  = bv;
          topid[rglob][cbase + it] = bj;
          cmask &= ~(1u << bt);
        }
      }
      {
        const float x = topv[rglob][lane & 31];
        float mx = x;
#pragma unroll
        for (int s = 16; s >= 1; s >>= 1) mx = fmaxf(mx, __shfl_xor(mx, s));
        const float e = expf(x - mx);
        float sum = e;
#pragma unroll
        for (int s = 16; s >= 1; s >>= 1) sum += __shfl_xor(sum, s);
        if (lane < KSEL) topv[rglob][lane] = e / sum;
      }
    }
    __syncthreads();
  }

  // write (attn, id) pairs, coalesced
#pragma unroll
  for (int pp = 0; pp < 2; ++pp) {
    const int idx = pp * 256 + tid;
    const int r = idx >> 5, k = idx & 31;
    pairs[((size_t)batch * NPTS + i0 + r) * KSEL + k] =
        make_float2(topv[r][k], __int_as_float(topid[r][k]));
  }
}

// ================= Kernel B: gather (broadcast-j, conflict-light) ===========
// 512 blocks x 256 threads; 32 rows/block; double-buffered global_load_lds.
__global__ __launch_bounds__(256, 2) void gnn_gather(const float* __restrict__ in,
                                                     const float2* __restrict__ pairs,
                                                     float* __restrict__ out) {
  __shared__ float fst[2][8 * 1028];   // 8 channel-rows per cc pass
  __shared__ float pr[32 * 68];        // [row][34 pairs]: a at 2k, j-bits at 2k+1

  const int p     = blockIdx.x;
  const int batch = ((p & 7) << 1) | ((p >> 3) & 1);
  const int chunk = p >> 4;            // 0..31
  const int i0    = chunk * 32;
  const int tid   = threadIdx.x;
  const int w     = tid >> 6;
  const int lane  = tid & 63;

  const float* __restrict__ fbase = in + (size_t)batch * CT * NPTS;

  // pairs -> LDS (1024 pairs = 512 float4)
  {
    const float4* pb4 = (const float4*)(pairs + ((size_t)batch * NPTS + i0) * KSEL);
#pragma unroll
    for (int h = 0; h < 2; ++h) {
      const int pidx = h * 256 + tid;          // float4 index: 2 pairs each
      const float4 q4 = pb4[pidx];
      const int r = pidx >> 4;                 // 16 float4 per row
      const int u = pidx & 15;
      *(float4*)&pr[r * 68 + u * 4] = q4;
    }
  }

  // stage helper: wave w stages channel-rows {2w, 2w+1} of pass cc into buf
#define STAGE(buf, ccv)                                                          \
  do {                                                                           \
    _Pragma("unroll")                                                            \
    for (int rr = 0; rr < 2; ++rr) {                                             \
      const int crow = w * 2 + rr;                                               \
      const float* src = fbase + (size_t)((ccv) * 8 + crow) * NPTS + lane * 4;   \
      float* dst = &fst[buf][crow * 1028];                                       \
      _Pragma("unroll")                                                          \
      for (int qq = 0; qq < 4; ++qq)                                             \
        __builtin_amdgcn_global_load_lds(                                        \
            (const __attribute__((address_space(1))) void*)(src + qq * 256),     \
            (__attribute__((address_space(3))) void*)(dst + qq * 256), 16, 0, 0);\
    }                                                                            \
  } while (0)

  STAGE(0, 0);
  asm volatile("s_waitcnt vmcnt(0)" ::: "memory");
  __syncthreads();

  const int c   = lane >> 3;           // channel slot 0..7
  const int rl  = lane & 7;
  const int row = w * 8 + rl;          // output row 0..31
  const float* prr = &pr[row * 68];

  for (int cc = 0; cc < 32; ++cc) {
    const int cur = cc & 1;
    if (cc < 31) STAGE(cur ^ 1, cc + 1);

    const float* fb = &fst[cur][c * 1028];
    float o = 0.f;
#pragma unroll
    for (int k = 0; k < KSEL; ++k) {
      const float2 pj = *(const float2*)&prr[2 * k];   // conflict-free broadcast
      o = fmaf(pj.x, fb[__float_as_int(pj.y)], o);     // 8 random j per instr
    }
    out[((size_t)batch * DFEAT + cc * 8 + c) * NPTS + i0 + row] = o;

    asm volatile("s_waitcnt vmcnt(0)" ::: "memory");
    __syncthreads();
  }
#undef STAGE
}

extern "C" void kernel_launch(void* const* d_in, const int* in_sizes, int n_in,
                              void* d_out, int out_size, void* d_ws, size_t ws_size,
                              hipStream_t stream) {
  const float* in = (const float*)d_in[0];
  float* out = (float*)d_out;
  float2* pairs = (float2*)d_ws;       // 16*1024*32*8B = 4 MB
  gnn_sim_topk<<<dim3(1024), dim3(256), 0, stream>>>(in, pairs);
  gnn_gather<<<dim3(512), dim3(256), 0, stream>>>(in, pairs, out);
}